// Round 2
// baseline (39404.132 us; speedup 1.0000x reference)
//
#include <hip/hip_runtime.h>

// Problem constants (match reference)
#define BB 16
#define SS 2048
#define DD 256
#define ND4 1024   // 4*D
#define LL 4

// ---------------------------------------------------------------------------
// Kernel 1: embed  h0[tok][d] = x[tok]*in_W[0][d] + sum_c tf[tok][c]*in_W[c+1][d] + in_b[d]
// ---------------------------------------------------------------------------
__global__ void embed_kernel(const float* __restrict__ x, const float* __restrict__ tf,
                             const float* __restrict__ inW, const float* __restrict__ inb,
                             float* __restrict__ h) {
    int tok = blockIdx.x;
    int d = threadIdx.x;
    float xv = x[tok];
    float acc = inb[d] + xv * inW[d];
#pragma unroll
    for (int c = 0; c < 6; ++c)
        acc = fmaf(tf[tok * 6 + c], inW[(c + 1) * DD + d], acc);
    h[(size_t)tok * DD + d] = acc;
}

// ---------------------------------------------------------------------------
// Kernel 2: per-token LN stats (biased var, matches jnp.var ddof=0)
// ---------------------------------------------------------------------------
__global__ void ln_stats_kernel(const float* __restrict__ h, float* __restrict__ mu,
                                float* __restrict__ rs) {
    int wave = threadIdx.x >> 6, lane = threadIdx.x & 63;
    int tok = blockIdx.x * 4 + wave;
    const float4 v = *(const float4*)(h + (size_t)tok * DD + lane * 4);
    float s = v.x + v.y + v.z + v.w;
    float ss = v.x * v.x + v.y * v.y + v.z * v.z + v.w * v.w;
#pragma unroll
    for (int off = 32; off; off >>= 1) {
        s += __shfl_down(s, off);
        ss += __shfl_down(ss, off);
    }
    if (lane == 0) {
        float mean = s * (1.f / 256.f);
        float var = ss * (1.f / 256.f) - mean * mean;
        mu[tok] = mean;
        rs[tok] = rsqrtf(var + 1e-5f);
    }
}

// ---------------------------------------------------------------------------
// Kernel 3: gx = LN(h)*g+b @ Wx + bg   (fp32 tiled GEMM, LN fused on A-load)
// ---------------------------------------------------------------------------
__global__ __launch_bounds__(256, 2) void gemm_gx_kernel(
    const float* __restrict__ h, const float* __restrict__ mu, const float* __restrict__ rs,
    const float* __restrict__ lng, const float* __restrict__ lnb,
    const float* __restrict__ Wx, const float* __restrict__ bg, float* __restrict__ gx) {
    const int rowBase = blockIdx.x * 128, nBase = blockIdx.y * 128;
    const int tid = threadIdx.x;
    const int tx = tid & 15, ty = tid >> 4;
    __shared__ float As[64][132];  // k-major: As[k][row]
    __shared__ float Bs[64][132];  // k-major: Bs[k][col]
    float acc[8][8] = {{0.f}};
    float bgv[8];
#pragma unroll
    for (int j = 0; j < 8; ++j) bgv[j] = bg[nBase + tx + 16 * j];

    for (int kc = 0; kc < 256; kc += 64) {
#pragma unroll
        for (int it = 0; it < 8; ++it) {
            int f = it * 256 + tid;
            int row = f >> 4;
            int kp = (f & 15) << 2;
            const float4 hv = *(const float4*)(h + (size_t)(rowBase + row) * DD + kc + kp);
            float muv = mu[rowBase + row], rsv = rs[rowBase + row];
            const float4 gv = *(const float4*)(lng + kc + kp);
            const float4 bv = *(const float4*)(lnb + kc + kp);
            As[kp + 0][row] = (hv.x - muv) * rsv * gv.x + bv.x;
            As[kp + 1][row] = (hv.y - muv) * rsv * gv.y + bv.y;
            As[kp + 2][row] = (hv.z - muv) * rsv * gv.z + bv.z;
            As[kp + 3][row] = (hv.w - muv) * rsv * gv.w + bv.w;
        }
#pragma unroll
        for (int it = 0; it < 8; ++it) {
            int f = it * 256 + tid;
            int kr = f >> 5;
            int cp = (f & 31) << 2;
            *(float4*)&Bs[kr][cp] = *(const float4*)(Wx + (size_t)(kc + kr) * ND4 + nBase + cp);
        }
        __syncthreads();
#pragma unroll 8
        for (int kk = 0; kk < 64; ++kk) {
            float a[8], b[8];
#pragma unroll
            for (int i = 0; i < 8; ++i) a[i] = As[kk][ty + 16 * i];
#pragma unroll
            for (int j = 0; j < 8; ++j) b[j] = Bs[kk][tx + 16 * j];
#pragma unroll
            for (int i = 0; i < 8; ++i)
#pragma unroll
                for (int j = 0; j < 8; ++j) acc[i][j] = fmaf(a[i], b[j], acc[i][j]);
        }
        __syncthreads();
    }
#pragma unroll
    for (int i = 0; i < 8; ++i) {
        size_t row = rowBase + ty + 16 * i;
#pragma unroll
        for (int j = 0; j < 8; ++j)
            gx[row * ND4 + nBase + tx + 16 * j] = acc[i][j] + bgv[j];
    }
}

// ---------------------------------------------------------------------------
// Kernel 4: sLSTM scan, one layer. 64 WGs (b = blk&15, q = blk>>4), 1024 thr.
// Changes vs R1 (theory: serialized polls were ~2-3k cyc of the 5.3k cyc step):
//  - P layout [parity][b][col][4]: one col's 4 slots in one 32B chunk
//  - all 3 partner polls issued per iteration (discovery = max RT, not sum)
//  - 2 barriers/step instead of 3
//  - rcp/exp-based tanh & sigmoid (no libm tanhf, no IEEE divides)
// ---------------------------------------------------------------------------
__global__ __launch_bounds__(1024, 4) void scan_kernel(
    const float* __restrict__ gx,           // [16][2048][1024]
    const float* __restrict__ Wh,           // [256][1024] layer slice
    float* __restrict__ h,                  // [16][2048][256] residual stream, in place
    unsigned long long* __restrict__ P,     // [2][16][1024][4] tagged partials
    int* __restrict__ abortFlag) {
    const int b = blockIdx.x & 15;
    const int q = blockIdx.x >> 4;          // 0..3
    const int col = threadIdx.x;            // 0..1023

    __shared__ float hs_lds[DD];
    __shared__ float gcol[ND4];

    float w[64];
    const float* wp = Wh + (size_t)(q << 6) * ND4 + col;
#pragma unroll
    for (int kk = 0; kk < 64; ++kk) w[kk] = wp[(size_t)kk * ND4];

    if (col < DD) hs_lds[col] = 0.f;
    float c = 0.f, n = 0.f, m = 0.f;

    const float* gxp = gx + (size_t)b * SS * ND4 + col;
    float* hb = h + (size_t)b * SS * DD;
    // slot chunk for this col, per parity: P[par][b][col][0..3]
    unsigned long long* C0 = P + ((size_t)(0 * 16 + b) * ND4 + col) * 4;
    unsigned long long* C1 = P + ((size_t)(1 * 16 + b) * ND4 + col) * 4;
    const int q1 = (q + 1) & 3, q2 = (q + 2) & 3, q3 = (q + 3) & 3;
    __syncthreads();

    for (int t = 0; t < SS; ++t) {
        const unsigned tag = (unsigned)(t + 1);
        unsigned long long* chunk = (t & 1) ? C1 : C0;
        // prefetch step inputs
        float gxv = gxp[(size_t)t * ND4];
        float hin = 0.f;
        if (col < DD) hin = hb[(size_t)t * DD + col];

        // K-slice dot product from LDS broadcast reads
        const float4* hv4 = (const float4*)(hs_lds + (q << 6));
        float a0 = 0.f, a1 = 0.f, a2 = 0.f, a3 = 0.f;
#pragma unroll
        for (int k4 = 0; k4 < 16; ++k4) {
            float4 hv = hv4[k4];
            a0 = fmaf(w[4 * k4 + 0], hv.x, a0);
            a1 = fmaf(w[4 * k4 + 1], hv.y, a1);
            a2 = fmaf(w[4 * k4 + 2], hv.z, a2);
            a3 = fmaf(w[4 * k4 + 3], hv.w, a3);
        }
        float part = (a0 + a1) + (a2 + a3);

        // publish tagged partial (payload+tag in one atom -> no fences)
        unsigned long long pv = ((unsigned long long)tag << 32) | (unsigned long long)__float_as_uint(part);
        __hip_atomic_store(chunk + q, pv, __ATOMIC_RELAXED, __HIP_MEMORY_SCOPE_AGENT);
        __asm__ volatile("" ::: "memory");

        // gather partner partials: all three polled each iteration
        unsigned long long v1, v2, v3;
        int guard = 0;
        for (;;) {
            v1 = __hip_atomic_load(chunk + q1, __ATOMIC_RELAXED, __HIP_MEMORY_SCOPE_AGENT);
            v2 = __hip_atomic_load(chunk + q2, __ATOMIC_RELAXED, __HIP_MEMORY_SCOPE_AGENT);
            v3 = __hip_atomic_load(chunk + q3, __ATOMIC_RELAXED, __HIP_MEMORY_SCOPE_AGENT);
            bool ok = ((unsigned)(v1 >> 32) == tag) & ((unsigned)(v2 >> 32) == tag) &
                      ((unsigned)(v3 >> 32) == tag);
            if (ok) break;
            if ((++guard & 1023) == 0) {
                if (guard > (1 << 19) ||
                    __hip_atomic_load(abortFlag, __ATOMIC_RELAXED, __HIP_MEMORY_SCOPE_AGENT)) {
                    __hip_atomic_store(abortFlag, 1, __ATOMIC_RELAXED, __HIP_MEMORY_SCOPE_AGENT);
                    break;  // bail (wrong answer, never a hang)
                }
            }
        }
        float gsum = part + gxv + __uint_as_float((unsigned)v1) +
                     __uint_as_float((unsigned)v2) + __uint_as_float((unsigned)v3);

        gcol[col] = gsum;          // prev-step gate reads of gcol finished before
        __syncthreads();           // last step's trailing barrier
        if (col < DD) {
            float gi = gcol[col], gf = gcol[DD + col], gz = gcol[2 * DD + col], go = gcol[3 * DD + col];
            float mn = fmaxf(gf + m, gi);
            float ip = __expf(gi - mn);
            float fp = __expf(gf + m - mn);
            float e2z = __expf(2.f * gz);
            float th = 1.f - 2.f * __builtin_amdgcn_rcpf(e2z + 1.f);   // tanh(gz)
            c = fp * c + ip * th;
            n = fp * n + ip;
            m = mn;
            float sg = __builtin_amdgcn_rcpf(1.f + __expf(-go));       // sigmoid(go)
            float hval = sg * c * __builtin_amdgcn_rcpf(fmaxf(fabsf(n), 1.f));
            hs_lds[col] = hval;
            if (q == (col >> 6)) hb[(size_t)t * DD + col] = hin + hval;  // residual
        }
        __syncthreads();           // hs_lds/gcol ready for next step
    }
}

// ---------------------------------------------------------------------------
// Kernel 5: out[b] = h[b][S-1][:] . fc_W + fc_b
// ---------------------------------------------------------------------------
__global__ void final_kernel(const float* __restrict__ h, const float* __restrict__ fcW,
                             const float* __restrict__ fcb, float* __restrict__ out) {
    int b = blockIdx.x, lane = threadIdx.x;
    const float4 hv = *(const float4*)(h + ((size_t)b * SS + (SS - 1)) * DD + lane * 4);
    const float4 wv = *(const float4*)(fcW + lane * 4);
    float s = hv.x * wv.x + hv.y * wv.y + hv.z * wv.z + hv.w * wv.w;
#pragma unroll
    for (int off = 32; off; off >>= 1) s += __shfl_down(s, off);
    if (lane == 0) out[b] = s + fcb[0];
}

// ---------------------------------------------------------------------------
extern "C" void kernel_launch(void* const* d_in, const int* in_sizes, int n_in,
                              void* d_out, int out_size, void* d_ws, size_t ws_size,
                              hipStream_t stream) {
    const float* x   = (const float*)d_in[0];
    const float* tf  = (const float*)d_in[1];
    const float* inW = (const float*)d_in[2];
    const float* inb = (const float*)d_in[3];
    const float* lng = (const float*)d_in[4];
    const float* lnb = (const float*)d_in[5];
    const float* Wx  = (const float*)d_in[6];
    const float* Wh  = (const float*)d_in[7];
    const float* bg  = (const float*)d_in[8];
    const float* fcW = (const float*)d_in[9];
    const float* fcb = (const float*)d_in[10];
    float* out = (float*)d_out;

    const size_t nTok = (size_t)BB * SS;                  // 32768
    float* h  = (float*)d_ws;                             // 8,388,608 f
    float* mu = h + nTok * DD;
    float* rs = mu + nTok;
    float* gxb = rs + nTok;                               // 33,554,432 f
    unsigned long long* P = (unsigned long long*)(gxb + nTok * ND4);  // 131072 u64
    int* abortFlag = (int*)(P + 2 * 16 * ND4 * 4);

    const size_t needed = (size_t)((char*)(abortFlag + 1) - (char*)d_ws);
    if (ws_size < needed) return;

    hipMemsetAsync(abortFlag, 0, sizeof(int), stream);
    // P needs no init: 0xAA poison never matches a tag in [1,2048]

    embed_kernel<<<nTok, DD, 0, stream>>>(x, tf, inW, inb, h);

    for (int l = 0; l < LL; ++l) {
        ln_stats_kernel<<<nTok / 4, 256, 0, stream>>>(h, mu, rs);
        gemm_gx_kernel<<<dim3(nTok / 128, ND4 / 128), 256, 0, stream>>>(
            h, mu, rs, lng + l * DD, lnb + l * DD,
            Wx + (size_t)l * DD * ND4, bg + l * ND4, gxb);
        scan_kernel<<<64, 1024, 0, stream>>>(
            gxb, Wh + (size_t)l * DD * ND4, h, P, abortFlag);
    }

    final_kernel<<<BB, 64, 0, stream>>>(h, fcW, fcb, out);
    (void)in_sizes; (void)n_in; (void)out_size;
}

// Round 3
// 21815.479 us; speedup vs baseline: 1.8062x; 1.8062x over previous
//
#include <hip/hip_runtime.h>

// Problem constants (match reference)
#define BB 16
#define SS 2048
#define DD 256
#define ND4 1024   // 4*D
#define LL 4

typedef __attribute__((ext_vector_type(8))) _Float16 half8;
typedef __attribute__((ext_vector_type(4))) float f32x4;
union H8 { half8 v; unsigned int u[4]; };

// ---------------------------------------------------------------------------
// Kernel 1: embed
// ---------------------------------------------------------------------------
__global__ void embed_kernel(const float* __restrict__ x, const float* __restrict__ tf,
                             const float* __restrict__ inW, const float* __restrict__ inb,
                             float* __restrict__ h) {
    int tok = blockIdx.x;
    int d = threadIdx.x;
    float xv = x[tok];
    float acc = inb[d] + xv * inW[d];
#pragma unroll
    for (int c = 0; c < 6; ++c)
        acc = fmaf(tf[tok * 6 + c], inW[(c + 1) * DD + d], acc);
    h[(size_t)tok * DD + d] = acc;
}

// ---------------------------------------------------------------------------
// Kernel 2: per-token LN stats
// ---------------------------------------------------------------------------
__global__ void ln_stats_kernel(const float* __restrict__ h, float* __restrict__ mu,
                                float* __restrict__ rs) {
    int wave = threadIdx.x >> 6, lane = threadIdx.x & 63;
    int tok = blockIdx.x * 4 + wave;
    const float4 v = *(const float4*)(h + (size_t)tok * DD + lane * 4);
    float s = v.x + v.y + v.z + v.w;
    float ss = v.x * v.x + v.y * v.y + v.z * v.z + v.w * v.w;
#pragma unroll
    for (int off = 32; off; off >>= 1) {
        s += __shfl_down(s, off);
        ss += __shfl_down(ss, off);
    }
    if (lane == 0) {
        float mean = s * (1.f / 256.f);
        float var = ss * (1.f / 256.f) - mean * mean;
        mu[tok] = mean;
        rs[tok] = rsqrtf(var + 1e-5f);
    }
}

// ---------------------------------------------------------------------------
// Kernel 3: gx = LN(h)*g+b @ Wx + bg  (fp32 tiled GEMM, unchanged from R1)
// ---------------------------------------------------------------------------
__global__ __launch_bounds__(256, 2) void gemm_gx_kernel(
    const float* __restrict__ h, const float* __restrict__ mu, const float* __restrict__ rs,
    const float* __restrict__ lng, const float* __restrict__ lnb,
    const float* __restrict__ Wx, const float* __restrict__ bg, float* __restrict__ gx) {
    const int rowBase = blockIdx.x * 128, nBase = blockIdx.y * 128;
    const int tid = threadIdx.x;
    const int tx = tid & 15, ty = tid >> 4;
    __shared__ float As[64][132];
    __shared__ float Bs[64][132];
    float acc[8][8] = {{0.f}};
    float bgv[8];
#pragma unroll
    for (int j = 0; j < 8; ++j) bgv[j] = bg[nBase + tx + 16 * j];

    for (int kc = 0; kc < 256; kc += 64) {
#pragma unroll
        for (int it = 0; it < 8; ++it) {
            int f = it * 256 + tid;
            int row = f >> 4;
            int kp = (f & 15) << 2;
            const float4 hv = *(const float4*)(h + (size_t)(rowBase + row) * DD + kc + kp);
            float muv = mu[rowBase + row], rsv = rs[rowBase + row];
            const float4 gv = *(const float4*)(lng + kc + kp);
            const float4 bv = *(const float4*)(lnb + kc + kp);
            As[kp + 0][row] = (hv.x - muv) * rsv * gv.x + bv.x;
            As[kp + 1][row] = (hv.y - muv) * rsv * gv.y + bv.y;
            As[kp + 2][row] = (hv.z - muv) * rsv * gv.z + bv.z;
            As[kp + 3][row] = (hv.w - muv) * rsv * gv.w + bv.w;
        }
#pragma unroll
        for (int it = 0; it < 8; ++it) {
            int f = it * 256 + tid;
            int kr = f >> 5;
            int cp = (f & 31) << 2;
            *(float4*)&Bs[kr][cp] = *(const float4*)(Wx + (size_t)(kc + kr) * ND4 + nBase + cp);
        }
        __syncthreads();
#pragma unroll 8
        for (int kk = 0; kk < 64; ++kk) {
            float a[8], b[8];
#pragma unroll
            for (int i = 0; i < 8; ++i) a[i] = As[kk][ty + 16 * i];
#pragma unroll
            for (int j = 0; j < 8; ++j) b[j] = Bs[kk][tx + 16 * j];
#pragma unroll
            for (int i = 0; i < 8; ++i)
#pragma unroll
                for (int j = 0; j < 8; ++j) acc[i][j] = fmaf(a[i], b[j], acc[i][j]);
        }
        __syncthreads();
    }
#pragma unroll
    for (int i = 0; i < 8; ++i) {
        size_t row = rowBase + ty + 16 * i;
#pragma unroll
        for (int j = 0; j < 8; ++j)
            gx[row * ND4 + nBase + tx + 16 * j] = acc[i][j] + bgv[j];
    }
}

// ---------------------------------------------------------------------------
// Kernel 4: sLSTM scan, batched-MFMA redesign.
// 16 WGs x 256 threads. WG g owns d in [16g,16g+16) for all 4 gates, all 16 b.
// Wave w (=gate w) holds Wh cols (w*256+16g+n') as fp16 B-frags in VGPRs.
// Exchange X[2][2048] u64: tag<<32 | 2xfp16 h values, laid out in MFMA
// A-frag order; each WG publishes a private contiguous 1KB region (full
// cachelines -> no false sharing, the R2 lesson). Reader lane's 32 tagged
// loads ARE its A-fragments (zero LDS for A). One barrier/step.
// ---------------------------------------------------------------------------
__global__ __launch_bounds__(256, 1) void scan_kernel(
    const float* __restrict__ gx,           // [16][2048][1024]
    const float* __restrict__ Wh,           // [256][1024] layer slice
    float* __restrict__ h,                  // [16][2048][256] residual stream
    unsigned long long* __restrict__ X,     // [2][2048] tagged fp16-pair atoms
    int* __restrict__ abortFlag, int tagBase) {
    const int g = blockIdx.x;               // 0..15
    const int tid = threadIdx.x;
    const int w = tid >> 6;                 // wave = gate index 0..3 (i,f,z,o)
    const int lane = tid & 63;
    const int mm = lane & 15;               // MFMA row (batch) / B col n'
    const int quad = lane >> 4;
    const int sb = tid >> 4;                // state role: batch 0..15
    const int sd = tid & 15;                // state role: d' 0..15
    const int dglob = g * 16 + sd;

    __shared__ float gbuf[2][4][16][16];    // [parity][gate][b][d'] 8KB

    // --- B fragments (once): B[k][n'] = Wh[k][w*256 + 16g + mm], fp16 ---
    H8 bfr[8];
    {
        const int col = w * 256 + g * 16 + mm;
#pragma unroll
        for (int kc = 0; kc < 8; ++kc) {
#pragma unroll
            for (int p = 0; p < 4; ++p) {
                float f0 = Wh[(size_t)(32 * kc + 8 * quad + 2 * p) * ND4 + col];
                float f1 = Wh[(size_t)(32 * kc + 8 * quad + 2 * p + 1) * ND4 + col];
                union { _Float16 hv; unsigned short u; } c0, c1;
                c0.hv = (_Float16)f0;
                c1.hv = (_Float16)f1;
                bfr[kc].u[p] = (unsigned)c0.u | ((unsigned)c1.u << 16);
            }
        }
    }

    float c_ = 0.f, n_ = 0.f, m_ = 0.f;     // sLSTM state for (sb, dglob)

    // publisher slot (even-sd threads publish pair (dglob, dglob+1) for sb)
    const int pquad = (dglob >> 3) & 3;
    const int ppair = (sd >> 1) & 3;
    const size_t pubIdx = (size_t)(g >> 1) * 256 + (size_t)pquad * 64 + (size_t)sb * 4 + ppair;
    const bool doPub = (sd & 1) == 0;
    // reader base: atoms for A-frag of (mm, quad): X[par][kc*256 + quad*64 + mm*4 + p]
    const size_t rdBase = (size_t)quad * 64 + (size_t)mm * 4;

    const float* gx0 = gx + (size_t)sb * SS * ND4 + dglob;
    float* hrow = h + (size_t)sb * SS * DD + dglob;

    for (int t = 0; t < SS; ++t) {
        // prefetch step inputs (independent of exchange)
        float gxi = gx0[(size_t)t * ND4];
        float gxf = gx0[(size_t)t * ND4 + 256];
        float gxz = gx0[(size_t)t * ND4 + 512];
        float gxo = gx0[(size_t)t * ND4 + 768];
        float hin = hrow[(size_t)t * DD];

        f32x4 acc0 = {0.f, 0.f, 0.f, 0.f}, acc1 = {0.f, 0.f, 0.f, 0.f};
        if (t > 0) {
            const unsigned tag = (unsigned)(tagBase + t);
            unsigned long long* Xp = X + (size_t)(t & 1) * 2048;
            unsigned long long v[32];
            int guard = 0;
            for (;;) {
#pragma unroll
                for (int kc = 0; kc < 8; ++kc)
#pragma unroll
                    for (int p = 0; p < 4; ++p)
                        v[kc * 4 + p] = __hip_atomic_load(Xp + (size_t)kc * 256 + rdBase + p,
                                                          __ATOMIC_RELAXED, __HIP_MEMORY_SCOPE_AGENT);
                bool ok = true;
#pragma unroll
                for (int i = 0; i < 32; ++i) ok &= ((unsigned)(v[i] >> 32) == tag);
                if (ok) break;
                if ((++guard & 255) == 0) {
                    if (guard > (1 << 17) ||
                        __hip_atomic_load(abortFlag, __ATOMIC_RELAXED, __HIP_MEMORY_SCOPE_AGENT)) {
                        __hip_atomic_store(abortFlag, 1, __ATOMIC_RELAXED, __HIP_MEMORY_SCOPE_AGENT);
                        break;  // bail: wrong answer, never a hang
                    }
                }
            }
            // A-frags directly from payload (low 32 bits = 2 fp16, k ascending)
            H8 afr[8];
#pragma unroll
            for (int kc = 0; kc < 8; ++kc)
#pragma unroll
                for (int p = 0; p < 4; ++p) afr[kc].u[p] = (unsigned)v[kc * 4 + p];
            // two interleaved 4-deep chains
            acc0 = __builtin_amdgcn_mfma_f32_16x16x32_f16(afr[0].v, bfr[0].v, acc0, 0, 0, 0);
            acc1 = __builtin_amdgcn_mfma_f32_16x16x32_f16(afr[1].v, bfr[1].v, acc1, 0, 0, 0);
            acc0 = __builtin_amdgcn_mfma_f32_16x16x32_f16(afr[2].v, bfr[2].v, acc0, 0, 0, 0);
            acc1 = __builtin_amdgcn_mfma_f32_16x16x32_f16(afr[3].v, bfr[3].v, acc1, 0, 0, 0);
            acc0 = __builtin_amdgcn_mfma_f32_16x16x32_f16(afr[4].v, bfr[4].v, acc0, 0, 0, 0);
            acc1 = __builtin_amdgcn_mfma_f32_16x16x32_f16(afr[5].v, bfr[5].v, acc1, 0, 0, 0);
            acc0 = __builtin_amdgcn_mfma_f32_16x16x32_f16(afr[6].v, bfr[6].v, acc0, 0, 0, 0);
            acc1 = __builtin_amdgcn_mfma_f32_16x16x32_f16(afr[7].v, bfr[7].v, acc1, 0, 0, 0);
        }
        f32x4 acc = acc0 + acc1;

        // C layout: col=lane&15 (=d'), row=quad*4+reg (=batch) -> gbuf[gate][b][d']
        const int par = t & 1;
#pragma unroll
        for (int r = 0; r < 4; ++r) gbuf[par][w][quad * 4 + r][mm] = acc[r];
        __syncthreads();

        // gate math on state threads (all 256 threads, one (b,d) each)
        float gi = gbuf[par][0][sb][sd] + gxi;
        float gf = gbuf[par][1][sb][sd] + gxf;
        float gz = gbuf[par][2][sb][sd] + gxz;
        float go = gbuf[par][3][sb][sd] + gxo;
        float mn = fmaxf(gf + m_, gi);
        float ip = __expf(gi - mn);
        float fp = __expf(gf + m_ - mn);
        float e2z = __expf(2.f * gz);
        float th = 1.f - 2.f * __builtin_amdgcn_rcpf(e2z + 1.f);     // tanh(gz)
        c_ = fp * c_ + ip * th;
        n_ = fp * n_ + ip;
        m_ = mn;
        float sg = __builtin_amdgcn_rcpf(1.f + __expf(-go));          // sigmoid(go)
        float hval = sg * c_ * __builtin_amdgcn_rcpf(fmaxf(fabsf(n_), 1.f));

        hrow[(size_t)t * DD] = hin + hval;   // residual stream (fp32)

        // publish h(t) as fp16 pair, tag t+1, parity (t+1)&1
        float hodd = __shfl_down(hval, 1);
        if (doPub) {
            union { _Float16 hv; unsigned short u; } ce, co;
            ce.hv = (_Float16)hval;
            co.hv = (_Float16)hodd;
            unsigned payload = (unsigned)ce.u | ((unsigned)co.u << 16);
            unsigned long long pv =
                ((unsigned long long)(unsigned)(tagBase + t + 1) << 32) | (unsigned long long)payload;
            __hip_atomic_store(X + (size_t)((t + 1) & 1) * 2048 + pubIdx, pv,
                               __ATOMIC_RELAXED, __HIP_MEMORY_SCOPE_AGENT);
        }
    }
}

// ---------------------------------------------------------------------------
// Kernel 5: out[b] = h[b][S-1][:] . fc_W + fc_b
// ---------------------------------------------------------------------------
__global__ void final_kernel(const float* __restrict__ h, const float* __restrict__ fcW,
                             const float* __restrict__ fcb, float* __restrict__ out) {
    int b = blockIdx.x, lane = threadIdx.x;
    const float4 hv = *(const float4*)(h + ((size_t)b * SS + (SS - 1)) * DD + lane * 4);
    const float4 wv = *(const float4*)(fcW + lane * 4);
    float s = hv.x * wv.x + hv.y * wv.y + hv.z * wv.z + hv.w * wv.w;
#pragma unroll
    for (int off = 32; off; off >>= 1) s += __shfl_down(s, off);
    if (lane == 0) out[b] = s + fcb[0];
}

// ---------------------------------------------------------------------------
extern "C" void kernel_launch(void* const* d_in, const int* in_sizes, int n_in,
                              void* d_out, int out_size, void* d_ws, size_t ws_size,
                              hipStream_t stream) {
    const float* x   = (const float*)d_in[0];
    const float* tf  = (const float*)d_in[1];
    const float* inW = (const float*)d_in[2];
    const float* inb = (const float*)d_in[3];
    const float* lng = (const float*)d_in[4];
    const float* lnb = (const float*)d_in[5];
    const float* Wx  = (const float*)d_in[6];
    const float* Wh  = (const float*)d_in[7];
    const float* bg  = (const float*)d_in[8];
    const float* fcW = (const float*)d_in[9];
    const float* fcb = (const float*)d_in[10];
    float* out = (float*)d_out;

    const size_t nTok = (size_t)BB * SS;                  // 32768
    float* h  = (float*)d_ws;                             // 8,388,608 f
    float* mu = h + nTok * DD;
    float* rs = mu + nTok;
    float* gxb = rs + nTok;                               // 33,554,432 f
    unsigned long long* X = (unsigned long long*)(gxb + nTok * ND4);  // 4096 u64
    int* abortFlag = (int*)(X + 2 * 2048);

    const size_t needed = (size_t)((char*)(abortFlag + 1) - (char*)d_ws);
    if (ws_size < needed) return;

    hipMemsetAsync(abortFlag, 0, sizeof(int), stream);
    // X needs no init: 0xAA poison never matches any tag (tags are < 4*2048+2049)

    embed_kernel<<<nTok, DD, 0, stream>>>(x, tf, inW, inb, h);

    for (int l = 0; l < LL; ++l) {
        ln_stats_kernel<<<nTok / 4, 256, 0, stream>>>(h, mu, rs);
        gemm_gx_kernel<<<dim3(nTok / 128, ND4 / 128), 256, 0, stream>>>(
            h, mu, rs, lng + l * DD, lnb + l * DD,
            Wx + (size_t)l * DD * ND4, bg + l * ND4, gxb);
        scan_kernel<<<16, 256, 0, stream>>>(
            gxb, Wh + (size_t)l * DD * ND4, h, X, abortFlag, l * SS);
    }

    final_kernel<<<BB, 64, 0, stream>>>(h, fcW, fcb, out);
    (void)in_sizes; (void)n_in; (void)out_size;
}

// Round 4
// 7232.896 us; speedup vs baseline: 5.4479x; 3.0161x over previous
//
#include <hip/hip_runtime.h>

// Problem constants
#define BB 16
#define SS 2048
#define DD 256
#define ND4 1024   // 4*D
#define PRD 16     // R-buffer slot depth (residual stream)
#define PGD 8      // GX-buffer slot depth (gate pre-activations)
#define HLP 4      // helper WGs per layer

typedef __attribute__((ext_vector_type(8))) _Float16 half8;
typedef __attribute__((ext_vector_type(4))) float f32x4;
typedef unsigned long long u64;
union H8 { half8 v; unsigned int u[4]; uint4 q; };

__device__ __forceinline__ u64 aload(const u64* p) {
    return __hip_atomic_load(p, __ATOMIC_RELAXED, __HIP_MEMORY_SCOPE_AGENT);
}
__device__ __forceinline__ void astore(u64* p, u64 v) {
    __hip_atomic_store(p, v, __ATOMIC_RELAXED, __HIP_MEMORY_SCOPE_AGENT);
}
__device__ __forceinline__ unsigned pload(const unsigned* p) {
    return __hip_atomic_load(p, __ATOMIC_RELAXED, __HIP_MEMORY_SCOPE_AGENT);
}
__device__ __forceinline__ void pstore(unsigned* p, unsigned v) {
    __hip_atomic_store(p, v, __ATOMIC_RELAXED, __HIP_MEMORY_SCOPE_AGENT);
}
__device__ __forceinline__ int aflag(int* p) {
    return __hip_atomic_load(p, __ATOMIC_RELAXED, __HIP_MEMORY_SCOPE_AGENT);
}
__device__ __forceinline__ void sflag(int* p) {
    __hip_atomic_store(p, 1, __ATOMIC_RELAXED, __HIP_MEMORY_SCOPE_AGENT);
}
__device__ __forceinline__ unsigned short f16b(float x) {
    union { _Float16 h; unsigned short u; } c; c.h = (_Float16)x; return c.u;
}
// spin guard with backoff for cross-layer polls (steady-state: first-try hit)
__device__ __forceinline__ bool spinBail(int& guard, int* af) {
    if ((++guard & 63) == 0) {
        __builtin_amdgcn_s_sleep(1);
        if (guard > (1 << 18) || aflag(af)) { sflag(af); return true; }
    }
    return false;
}

// ---------------------------------------------------------------------------
// embed: h0 = [x | tf] @ in_W + in_b
// ---------------------------------------------------------------------------
__global__ void embed_kernel(const float* __restrict__ x, const float* __restrict__ tf,
                             const float* __restrict__ inW, const float* __restrict__ inb,
                             float* __restrict__ h) {
    int tok = blockIdx.x, d = threadIdx.x;
    float xv = x[tok];
    float acc = inb[d] + xv * inW[d];
#pragma unroll
    for (int c = 0; c < 6; ++c)
        acc = fmaf(tf[tok * 6 + c], inW[(c + 1) * DD + d], acc);
    h[(size_t)tok * DD + d] = acc;
}

// ---------------------------------------------------------------------------
// Wx -> fp16 B-fragment order: Wxh[((l*64+G)*8+kc)*64 + lane][8]
// lane=(quad,mm): element i is Wx[l][kc*32+quad*8+i][G*16+mm]
// ---------------------------------------------------------------------------
__global__ void wxprep_kernel(const float* __restrict__ Wx, unsigned short* __restrict__ Wxh) {
    int l = blockIdx.x >> 6, G = blockIdx.x & 63;
    int lane = threadIdx.x, quad = lane >> 4, mm = lane & 15;
    const float* W = Wx + (size_t)l * DD * ND4;
    unsigned short* o = Wxh + (size_t)blockIdx.x * 4096;
#pragma unroll
    for (int kc = 0; kc < 8; ++kc) {
        __align__(16) unsigned short tmp[8];
#pragma unroll
        for (int i = 0; i < 8; ++i)
            tmp[i] = f16b(W[(size_t)(kc * 32 + quad * 8 + i) * ND4 + G * 16 + mm]);
        *(uint4*)(o + ((size_t)kc * 64 + lane) * 8) = *(uint4*)tmp;
    }
}

// ---------------------------------------------------------------------------
// Mega kernel: 80 WGs x 256 thr.
//   bid 0..63 : scan WG (layer l=bid>>4, g=bid&15) — R3-proven internals.
//   bid 64..79: helper WG (layer l=(bid-64)>>2, j=(bid-64)&3): streams
//               gx[l][t]=LN(r[l-1][t])@Wx[l]+bg for t ≡ j (mod 4).
// Dataflow (all tagged u64 atoms, tag = t+1, cacheline-private per writer):
//   X[l][2][2048]  : fp16-pair h_s exchange within layer (R3 mechanism)
//   R[l][16][4096] : fp32 residual stream r_l (scan l -> helper/scan l+1)
//   GX[l][8][16384]: fp32 gate pre-acts (helper l -> scan l)
// Slot reuse gated by progress atomics (prog[0..3]=scan, prog[4+l*4+j]=helper).
// ---------------------------------------------------------------------------
__global__ __launch_bounds__(256, 1) void mega_kernel(
    const float* __restrict__ hemb, const float* __restrict__ Wh,
    const float* __restrict__ lng, const float* __restrict__ lnb,
    const float* __restrict__ bgp, const unsigned short* __restrict__ Wxh,
    float* __restrict__ hout,
    u64* __restrict__ Xbuf, u64* __restrict__ Rbuf, u64* __restrict__ GXbuf,
    unsigned* __restrict__ prog, int* __restrict__ abortFlag) {
    __shared__ __align__(16) char smemBlob[57344];  // 56KB: forces <=2 WGs/CU
    const int bid = blockIdx.x;
    const int tid = threadIdx.x;

    if (bid < 64) {
        // ================= SCAN ROLE (R3 internals) =================
        const int l = bid >> 4, g = bid & 15;
        const int w = tid >> 6, lane = tid & 63;
        const int mm = lane & 15, quad = lane >> 4;
        const int sb = tid >> 4, sd = tid & 15;
        const int dglob = g * 16 + sd;
        float (*gbuf)[4][16][16] = (float (*)[4][16][16])smemBlob;

        H8 bfr[8];
        {
            const float* WhL = Wh + (size_t)l * DD * ND4;
            const int col = w * 256 + g * 16 + mm;
#pragma unroll
            for (int kc = 0; kc < 8; ++kc)
#pragma unroll
                for (int p = 0; p < 4; ++p) {
                    float f0 = WhL[(size_t)(32 * kc + 8 * quad + 2 * p) * ND4 + col];
                    float f1 = WhL[(size_t)(32 * kc + 8 * quad + 2 * p + 1) * ND4 + col];
                    bfr[kc].u[p] = (unsigned)f16b(f0) | ((unsigned)f16b(f1) << 16);
                }
        }

        float c_ = 0.f, n_ = 0.f, m_ = 0.f;

        u64* Xl = Xbuf + (size_t)l * 4096;
        const u64* Rprev = Rbuf + (size_t)(l > 0 ? l - 1 : 0) * PRD * 4096;
        u64* Rcur = Rbuf + (size_t)(l < 3 ? l : 0) * PRD * 4096;
        const u64* GXl = GXbuf + (size_t)l * PGD * 16384;

        const int pquad = (dglob >> 3) & 3;
        const int ppair = (sd >> 1) & 3;
        const size_t pubIdx = (size_t)(g >> 1) * 256 + (size_t)pquad * 64 + (size_t)sb * 4 + ppair;
        const bool doPub = (sd & 1) == 0;
        const size_t rdBase = (size_t)quad * 64 + (size_t)mm * 4;
        const size_t gxIdx = (size_t)sb * 1024 + dglob;
        const size_t rIdx = (size_t)sb * 256 + dglob;
        const float* hemb0 = hemb + (size_t)sb * SS * DD + dglob;
        float* hrow = hout + (size_t)sb * SS * DD + dglob;
        __syncthreads();

        for (int t = 0; t < SS; ++t) {
            const unsigned tagT = (unsigned)(t + 1);
            // ---- acquire gx (+ hin residual for l>0) ----
            float gxi, gxf, gxz, gxoo, hin;
            {
                const u64* Gp = GXl + (size_t)(t & (PGD - 1)) * 16384 + gxIdx;
                const u64* Rp = Rprev + (size_t)(t & (PRD - 1)) * 4096 + rIdx;
                u64 a0, a1, a2, a3, ar = 0;
                int guard = 0;
                for (;;) {
                    a0 = aload(Gp); a1 = aload(Gp + 256);
                    a2 = aload(Gp + 512); a3 = aload(Gp + 768);
                    if (l > 0) ar = aload(Rp);
                    bool ok = ((unsigned)(a0 >> 32) == tagT) & ((unsigned)(a1 >> 32) == tagT) &
                              ((unsigned)(a2 >> 32) == tagT) & ((unsigned)(a3 >> 32) == tagT) &
                              ((l == 0) | ((unsigned)(ar >> 32) == tagT));
                    if (ok) break;
                    if (spinBail(guard, abortFlag)) break;
                }
                gxi = __uint_as_float((unsigned)a0);
                gxf = __uint_as_float((unsigned)a1);
                gxz = __uint_as_float((unsigned)a2);
                gxoo = __uint_as_float((unsigned)a3);
                hin = (l > 0) ? __uint_as_float((unsigned)ar) : hemb0[(size_t)t * DD];
            }
            // ---- Wh matmul on h_s(t-1) via X exchange (R3) ----
            f32x4 acc0 = {0.f, 0.f, 0.f, 0.f}, acc1 = {0.f, 0.f, 0.f, 0.f};
            if (t > 0) {
                const unsigned tag = (unsigned)t;
                u64* Xp = Xl + (size_t)(t & 1) * 2048;
                u64 v[32];
                int guard = 0;
                for (;;) {
#pragma unroll
                    for (int kc = 0; kc < 8; ++kc)
#pragma unroll
                        for (int p = 0; p < 4; ++p)
                            v[kc * 4 + p] = aload(Xp + (size_t)kc * 256 + rdBase + p);
                    bool ok = true;
#pragma unroll
                    for (int i = 0; i < 32; ++i) ok &= ((unsigned)(v[i] >> 32) == tag);
                    if (ok) break;
                    if ((++guard & 255) == 0) {
                        if (guard > (1 << 18) || aflag(abortFlag)) { sflag(abortFlag); break; }
                    }
                }
                H8 afr[8];
#pragma unroll
                for (int kc = 0; kc < 8; ++kc)
#pragma unroll
                    for (int p = 0; p < 4; ++p) afr[kc].u[p] = (unsigned)v[kc * 4 + p];
                acc0 = __builtin_amdgcn_mfma_f32_16x16x32_f16(afr[0].v, bfr[0].v, acc0, 0, 0, 0);
                acc1 = __builtin_amdgcn_mfma_f32_16x16x32_f16(afr[1].v, bfr[1].v, acc1, 0, 0, 0);
                acc0 = __builtin_amdgcn_mfma_f32_16x16x32_f16(afr[2].v, bfr[2].v, acc0, 0, 0, 0);
                acc1 = __builtin_amdgcn_mfma_f32_16x16x32_f16(afr[3].v, bfr[3].v, acc1, 0, 0, 0);
                acc0 = __builtin_amdgcn_mfma_f32_16x16x32_f16(afr[4].v, bfr[4].v, acc0, 0, 0, 0);
                acc1 = __builtin_amdgcn_mfma_f32_16x16x32_f16(afr[5].v, bfr[5].v, acc1, 0, 0, 0);
                acc0 = __builtin_amdgcn_mfma_f32_16x16x32_f16(afr[6].v, bfr[6].v, acc0, 0, 0, 0);
                acc1 = __builtin_amdgcn_mfma_f32_16x16x32_f16(afr[7].v, bfr[7].v, acc1, 0, 0, 0);
            }
            f32x4 acc = acc0 + acc1;
            const int par = t & 1;
#pragma unroll
            for (int r = 0; r < 4; ++r) gbuf[par][w][quad * 4 + r][mm] = acc[r];
            __syncthreads();
            // ---- gates (R3 numerics) ----
            float gi = gbuf[par][0][sb][sd] + gxi;
            float gf = gbuf[par][1][sb][sd] + gxf;
            float gz = gbuf[par][2][sb][sd] + gxz;
            float go = gbuf[par][3][sb][sd] + gxoo;
            float mn = fmaxf(gf + m_, gi);
            float ip = __expf(gi - mn);
            float fp = __expf(gf + m_ - mn);
            float e2z = __expf(2.f * gz);
            float th = 1.f - 2.f * __builtin_amdgcn_rcpf(e2z + 1.f);
            c_ = fp * c_ + ip * th;
            n_ = fp * n_ + ip;
            m_ = mn;
            float sg = __builtin_amdgcn_rcpf(1.f + __expf(-go));
            float hval = sg * c_ * __builtin_amdgcn_rcpf(fmaxf(fabsf(n_), 1.f));
            float rnew = hin + hval;
            // ---- residual out ----
            if (l == 3) {
                hrow[(size_t)t * DD] = rnew;
            } else {
                if (t >= PRD) {  // slot-reuse gate: downstream must have passed t-PRD
                    unsigned needT = (unsigned)(t - PRD);
                    const unsigned* ps = prog + (l + 1);
                    const unsigned* pg = prog + 4 + (l + 1) * 4 + (int)(needT & (HLP - 1));
                    int guard = 0;
                    while (!((pload(ps) >= needT + 2) && (pload(pg) >= needT + 1))) {
                        if (spinBail(guard, abortFlag)) break;
                    }
                }
                astore(Rcur + (size_t)(t & (PRD - 1)) * 4096 + rIdx,
                       ((u64)tagT << 32) | (u64)__float_as_uint(rnew));
            }
            // ---- publish h_s(t) for step t+1 (R3) ----
            float hodd = __shfl_down(hval, 1);
            if (doPub) {
                unsigned payload = (unsigned)f16b(hval) | ((unsigned)f16b(hodd) << 16);
                astore(Xl + (size_t)((t + 1) & 1) * 2048 + pubIdx, ((u64)tagT << 32) | payload);
            }
            __syncthreads();
            if (g == 0 && tid == 0) pstore(prog + l, (unsigned)(t + 1));
        }
    } else {
        // ================= HELPER ROLE: streaming gx GEMM =================
        const int hix = bid - 64;
        const int l = hix >> 2;    // 0..3
        const int j = hix & 3;
        const int w = tid >> 6, lane = tid & 63;
        const int mm = lane & 15, quad = lane >> 4;
        const int hb_ = tid >> 4, hd0 = (tid & 15) * 16;
        unsigned short (*hA)[264] = (unsigned short (*)[264])smemBlob;

        const u64* Rin = Rbuf + (size_t)(l > 0 ? l - 1 : 0) * PRD * 4096;
        u64* GXl = GXbuf + (size_t)l * PGD * 16384;
        const unsigned short* WxL = Wxh + (size_t)l * 262144;
        const float* lngL = lng + l * DD;
        const float* lnbL = lnb + l * DD;
        const float* bgL = bgp + (size_t)l * ND4;
        unsigned* myProg = prog + 4 + l * 4 + j;
        const unsigned* scanProg = prog + l;

        for (int t = j; t < SS; t += HLP) {
            const unsigned tagT = (unsigned)(t + 1);
            // ---- 1. acquire r[l-1][t] (or embed for l==0) ----
            float rv[16];
            if (l == 0) {
                const float4* p = (const float4*)(hemb + ((size_t)hb_ * SS + t) * DD + hd0);
#pragma unroll
                for (int q4 = 0; q4 < 4; ++q4) {
                    float4 f = p[q4];
                    rv[q4 * 4 + 0] = f.x; rv[q4 * 4 + 1] = f.y;
                    rv[q4 * 4 + 2] = f.z; rv[q4 * 4 + 3] = f.w;
                }
            } else {
                const u64* Rp = Rin + (size_t)(t & (PRD - 1)) * 4096 + (size_t)tid * 16;
                int guard = 0;
                for (;;) {
                    u64 vv[16];
#pragma unroll
                    for (int i = 0; i < 16; ++i) vv[i] = aload(Rp + i);
                    bool ok = true;
#pragma unroll
                    for (int i = 0; i < 16; ++i) ok &= ((unsigned)(vv[i] >> 32) == tagT);
                    if (ok) {
#pragma unroll
                        for (int i = 0; i < 16; ++i) rv[i] = __uint_as_float((unsigned)vv[i]);
                        break;
                    }
                    if (spinBail(guard, abortFlag)) {
#pragma unroll
                        for (int i = 0; i < 16; ++i) rv[i] = 0.f;
                        break;
                    }
                }
            }
            // ---- 2. LN stats (16 threads per batch, shfl-xor reduce) ----
            float s = 0.f, ssq = 0.f;
#pragma unroll
            for (int i = 0; i < 16; ++i) { s += rv[i]; ssq += rv[i] * rv[i]; }
#pragma unroll
            for (int msk = 1; msk < 16; msk <<= 1) {
                s += __shfl_xor(s, msk);
                ssq += __shfl_xor(ssq, msk);
            }
            float muv = s * (1.f / 256.f);
            float rsv = rsqrtf(fmaxf(ssq * (1.f / 256.f) - muv * muv, 0.f) + 1e-5f);
            // ---- 3. LN -> fp16 -> LDS (A-matrix rows = batches) ----
            {
                __align__(16) unsigned short ov[16];
#pragma unroll
                for (int i = 0; i < 16; ++i)
                    ov[i] = f16b((rv[i] - muv) * rsv * lngL[hd0 + i] + lnbL[hd0 + i]);
                *(uint4*)&hA[hb_][hd0] = *(uint4*)&ov[0];
                *(uint4*)&hA[hb_][hd0 + 8] = *(uint4*)&ov[8];
            }
            __syncthreads();
            // ---- 4. A-frags from LDS ----
            H8 A[8];
#pragma unroll
            for (int kc = 0; kc < 8; ++kc)
                A[kc].q = *(const uint4*)&hA[mm][kc * 32 + quad * 8];
            // ---- 5. 16 tiles x 8 chunks MFMA, B streamed from L2 ----
            f32x4 acc[16];
            const unsigned short* WxW = WxL + (size_t)w * 16 * 4096;
#pragma unroll
            for (int n = 0; n < 16; ++n) {
                const unsigned short* bp = WxW + (size_t)n * 4096 + (size_t)lane * 8;
                f32x4 a = {0.f, 0.f, 0.f, 0.f};
#pragma unroll
                for (int kc = 0; kc < 8; ++kc) {
                    H8 B;
                    B.q = *(const uint4*)(bp + (size_t)kc * 512);
                    a = __builtin_amdgcn_mfma_f32_16x16x32_f16(A[kc].v, B.v, a, 0, 0, 0);
                }
                acc[n] = a;
            }
            // ---- 6. slot-reuse gate, then write GX ----
            if (t >= PGD) {
                unsigned need = (unsigned)(t - PGD) + 2;
                int guard = 0;
                while (pload(scanProg) < need) {
                    if (spinBail(guard, abortFlag)) break;
                }
            }
            u64* Gq = GXl + (size_t)(t & (PGD - 1)) * 16384;
#pragma unroll
            for (int n = 0; n < 16; ++n) {
                int c = (w * 16 + n) * 16 + mm;
                float bgv = bgL[c];
                f32x4 a = acc[n];
#pragma unroll
                for (int r = 0; r < 4; ++r)
                    astore(Gq + (size_t)(quad * 4 + r) * 1024 + c,
                           ((u64)tagT << 32) | (u64)__float_as_uint(a[r] + bgv));
            }
            __syncthreads();  // covers hA WAR for next token + read-phase completion
            if (tid == 0) pstore(myProg, (unsigned)(t + 1));
        }
    }
}

// ---------------------------------------------------------------------------
// final: out[b] = r3[b][S-1][:] . fc_W + fc_b
// ---------------------------------------------------------------------------
__global__ void final_kernel(const float* __restrict__ h, const float* __restrict__ fcW,
                             const float* __restrict__ fcb, float* __restrict__ out) {
    int b = blockIdx.x, lane = threadIdx.x;
    const float4 hv = *(const float4*)(h + ((size_t)b * SS + (SS - 1)) * DD + lane * 4);
    const float4 wv = *(const float4*)(fcW + lane * 4);
    float s = hv.x * wv.x + hv.y * wv.y + hv.z * wv.z + hv.w * wv.w;
#pragma unroll
    for (int off = 32; off; off >>= 1) s += __shfl_down(s, off);
    if (lane == 0) out[b] = s + fcb[0];
}

// ---------------------------------------------------------------------------
extern "C" void kernel_launch(void* const* d_in, const int* in_sizes, int n_in,
                              void* d_out, int out_size, void* d_ws, size_t ws_size,
                              hipStream_t stream) {
    const float* x   = (const float*)d_in[0];
    const float* tf  = (const float*)d_in[1];
    const float* inW = (const float*)d_in[2];
    const float* inb = (const float*)d_in[3];
    const float* lng = (const float*)d_in[4];
    const float* lnb = (const float*)d_in[5];
    const float* Wx  = (const float*)d_in[6];
    const float* Wh  = (const float*)d_in[7];
    const float* bg  = (const float*)d_in[8];
    const float* fcW = (const float*)d_in[9];
    const float* fcb = (const float*)d_in[10];
    float* out = (float*)d_out;

    const size_t nTok = (size_t)BB * SS;
    float* hemb = (float*)d_ws;                                   // 8,388,608 f
    float* hout = hemb + nTok * DD;                               // 8,388,608 f
    unsigned short* Wxh = (unsigned short*)(hout + nTok * DD);    // 1,048,576 us
    u64* Xbuf = (u64*)(Wxh + 1048576);                            // 4*2*2048
    u64* Rbuf = Xbuf + 4 * 2 * 2048;                              // 3*16*4096
    u64* GXbuf = Rbuf + 3 * PRD * 4096;                           // 4*8*16384
    unsigned* prog = (unsigned*)(GXbuf + 4 * PGD * 16384);        // 20 u32
    int* abortFlag = (int*)(prog + 20);

    const size_t needed = (size_t)((char*)(abortFlag + 1) - (char*)d_ws);
    if (ws_size < needed) return;  // fail visibly instead of corrupting

    hipMemsetAsync(prog, 0, 20 * sizeof(unsigned) + sizeof(int), stream);
    // X/R/GX need no init: 0xAA poison never matches a tag in [1,2048]

    embed_kernel<<<nTok, DD, 0, stream>>>(x, tf, inW, inb, hemb);
    wxprep_kernel<<<4 * 64, 64, 0, stream>>>(Wx, Wxh);
    mega_kernel<<<80, 256, 0, stream>>>(hemb, Wh, lng, lnb, bg, Wxh, hout,
                                        Xbuf, Rbuf, GXbuf, prog, abortFlag);
    final_kernel<<<BB, 64, 0, stream>>>(hout, fcW, fcb, out);
    (void)in_sizes; (void)n_in; (void)out_size;
}